// Round 6
// baseline (508.460 us; speedup 1.0000x reference)
//
#include <hip/hip_runtime.h>
#include <hip/hip_bf16.h>

#define VV 100000
#define EE 50
#define HH 64
#define BB 1024
#define TT 200
// 3H = 192

typedef float v4f __attribute__((ext_vector_type(4)));

__device__ __forceinline__ float fsig(float x) {
    return 1.f / (1.f + __expf(-x));
}
__device__ __forceinline__ float ftanh(float x) {
    float e = __expf(2.f * x);
    return 1.f - 2.f / (e + 1.f);
}
__device__ __forceinline__ void pin(float& x) { asm volatile("" : "+v"(x)); }

// ---------------- Kernel A: embW[v][c] = emb[v][:] @ Wx[:,c] + bi[c]  (both dirs via blockIdx.y) ----------------
__global__ __launch_bounds__(256) void embw_kernel(
    const float* __restrict__ emb,
    const float* __restrict__ Wx_f, const float* __restrict__ bi_f,
    const float* __restrict__ Wx_b, const float* __restrict__ bi_b,
    float* __restrict__ embW_f, float* __restrict__ embW_b)
{
    const float* Wx = blockIdx.y ? Wx_b : Wx_f;
    const float* bi = blockIdx.y ? bi_b : bi_f;
    float* embW     = blockIdx.y ? embW_b : embW_f;
    __shared__ float wx_lds[EE * 192];
    __shared__ float emb_lds[32 * EE];
    const int tid = threadIdx.x;
    const int v0 = blockIdx.x * 32;
    for (int i = tid; i < EE * 192; i += 256) wx_lds[i] = Wx[i];
    for (int i = tid; i < 32 * EE; i += 256) emb_lds[i] = emb[(size_t)v0 * EE + i];
    __syncthreads();
    const int cg = tid & 63;
    const int rg = tid >> 6;
    float acc[8][3];
    #pragma unroll
    for (int i = 0; i < 8; i++) {
        acc[i][0] = bi[cg];
        acc[i][1] = bi[cg + 64];
        acc[i][2] = bi[cg + 128];
    }
    for (int k = 0; k < EE; k++) {
        const float wx0 = wx_lds[k * 192 + cg];
        const float wx1 = wx_lds[k * 192 + cg + 64];
        const float wx2 = wx_lds[k * 192 + cg + 128];
        #pragma unroll
        for (int i = 0; i < 8; i++) {
            const float ev = emb_lds[(rg * 8 + i) * EE + k];
            acc[i][0] = fmaf(ev, wx0, acc[i][0]);
            acc[i][1] = fmaf(ev, wx1, acc[i][1]);
            acc[i][2] = fmaf(ev, wx2, acc[i][2]);
        }
    }
    #pragma unroll
    for (int i = 0; i < 8; i++) {
        const size_t row = (size_t)(v0 + rg * 8 + i) * 192;
        embW[row + cg]       = acc[i][0];
        embW[row + cg + 64]  = acc[i][1];
        embW[row + cg + 128] = acc[i][2];
    }
}

// ---------------- Kernel B v4: one wave per (sequence, direction); opaque register weights ----
__device__ __forceinline__ void opaque(v4f& x) {
    float a = x[0], b = x[1], c = x[2], d = x[3];
    asm volatile("" : "+v"(a), "+v"(b), "+v"(c), "+v"(d));
    x[0] = a; x[1] = b; x[2] = c; x[3] = d;
}
#define DECL_W(i) \
    v4f wz##i = {Wh[(4*i+0)*192+j],     Wh[(4*i+1)*192+j],     Wh[(4*i+2)*192+j],     Wh[(4*i+3)*192+j]};     \
    v4f wr##i = {Wh[(4*i+0)*192+64+j],  Wh[(4*i+1)*192+64+j],  Wh[(4*i+2)*192+64+j],  Wh[(4*i+3)*192+64+j]};  \
    v4f wn##i = {Wh[(4*i+0)*192+128+j], Wh[(4*i+1)*192+128+j], Wh[(4*i+2)*192+128+j], Wh[(4*i+3)*192+128+j]}; \
    opaque(wz##i); opaque(wr##i); opaque(wn##i);

#define GSTEP(i) { const v4f hv = h4[i]; \
    aZ = __builtin_elementwise_fma(hv, wz##i, aZ); \
    aR = __builtin_elementwise_fma(hv, wr##i, aR); \
    aN = __builtin_elementwise_fma(hv, wn##i, aN); }

__global__ __launch_bounds__(64, 2) void gru4_kernel(
    const int* __restrict__ ids,
    const float* __restrict__ embW_f, const float* __restrict__ embW_b,
    const float* __restrict__ Wh_f, const float* __restrict__ br_f,
    const float* __restrict__ Wh_b, const float* __restrict__ br_b,
    float* __restrict__ outb,     // [B, T, 128]
    float* __restrict__ hf_out)   // [B, 64]
{
    const int j   = threadIdx.x;
    const int b   = blockIdx.x;
    const int dir = blockIdx.y;
    const float* eW = dir ? embW_b : embW_f;
    const float* Wh = dir ? Wh_b : Wh_f;
    const float* br = dir ? br_b : br_f;

    DECL_W(0)  DECL_W(1)  DECL_W(2)  DECL_W(3)
    DECL_W(4)  DECL_W(5)  DECL_W(6)  DECL_W(7)
    DECL_W(8)  DECL_W(9)  DECL_W(10) DECL_W(11)
    DECL_W(12) DECL_W(13) DECL_W(14) DECL_W(15)
    const float brz = br[j], brr = br[64 + j], brn = br[128 + j];

    __shared__ __align__(16) float h_lds[64];
    __shared__ int ids_lds[TT];
    for (int i = j; i < TT; i += 64) ids_lds[i] = ids[(size_t)b * TT + i];
    h_lds[j] = 0.f;
    float hj = 0.f;
    __syncthreads();   // one-time; none inside the step loop

    const int t0 = dir ? (TT - 1) : 0;
    const int dt = dir ? -1 : 1;

    int   id0 = ids_lds[t0];
    float gz0 = eW[(size_t)id0 * 192 + j];
    float gr0 = eW[(size_t)id0 * 192 + 64 + j];
    float gn0 = eW[(size_t)id0 * 192 + 128 + j];
    int   id1 = ids_lds[t0 + dt];
    float gz1 = eW[(size_t)id1 * 192 + j];
    float gr1 = eW[(size_t)id1 * 192 + 64 + j];
    float gn1 = eW[(size_t)id1 * 192 + 128 + j];

    float* obase = outb + (size_t)b * TT * 128 + dir * 64 + j;

    for (int s = 0; s < TT; s++) {
        const int t = t0 + s * dt;
        int id2 = 0; float gz2 = 0.f, gr2 = 0.f, gn2 = 0.f;
        if (s + 2 < TT) {
            id2 = ids_lds[t + 2 * dt];
            gz2 = eW[(size_t)id2 * 192 + j];
            gr2 = eW[(size_t)id2 * 192 + 64 + j];
            gn2 = eW[(size_t)id2 * 192 + 128 + j];
        }
        v4f aZ = {brz, 0.f, 0.f, 0.f};
        v4f aR = {brr, 0.f, 0.f, 0.f};
        v4f aN = {brn, 0.f, 0.f, 0.f};
        const v4f* h4 = (const v4f*)h_lds;
        GSTEP(0)  GSTEP(1)  GSTEP(2)  GSTEP(3)
        GSTEP(4)  GSTEP(5)  GSTEP(6)  GSTEP(7)
        GSTEP(8)  GSTEP(9)  GSTEP(10) GSTEP(11)
        GSTEP(12) GSTEP(13) GSTEP(14) GSTEP(15)
        const float az = (aZ[0] + aZ[1]) + (aZ[2] + aZ[3]);
        const float ar = (aR[0] + aR[1]) + (aR[2] + aR[3]);
        const float an = (aN[0] + aN[1]) + (aN[2] + aN[3]);
        const float z  = fsig(gz0 + az);
        const float r  = fsig(gr0 + ar);
        const float hh = ftanh(gn0 + r * an);
        float hnew = z * hj + (1.f - z) * hh;
        hnew = (id0 != 0) ? hnew : hj;
        hj = hnew;
        h_lds[j] = hj;
        obase[(size_t)t * 128] = hj;
        id0 = id1; gz0 = gz1; gr0 = gr1; gn0 = gn1;
        id1 = id2; gz1 = gz2; gr1 = gr2; gn1 = gn2;
    }
    if (dir == 0) hf_out[(size_t)b * 64 + j] = hj;
}

// ---------------- Kernel C v6: 8-wave keys GEMM, 16 weight regs/lane (spill-proof) ----------------
// Block = 512 thr (8 waves), one per batch row b. Wave w owns cols [8w, 8w+8).
// Lane l: cl = l&7 -> col c = 8w+cl; h = l>>3 -> Wk rows [16h, 16h+16).
// Dot combined over h via shfl_xor(8,16,32); energy summed over cl via shfl_xor(1,2,4).
__global__ __launch_bounds__(512, 4) void attn6_kernel(
    const int* __restrict__ ids,
    const float* __restrict__ outb,   // [B,T,128]
    const float* __restrict__ hf,     // [B,64]
    const float* __restrict__ Wk, const float* __restrict__ bk,
    const float* __restrict__ Wq, const float* __restrict__ bq,
    const float* __restrict__ We, const float* __restrict__ be,
    float* __restrict__ ctx)          // [B,128]
{
    __shared__ float epart[8][TT];
    __shared__ float e_lds[TT];
    __shared__ float part[8][128];
    const int b = blockIdx.x;
    const int tid = threadIdx.x;
    const int w = tid >> 6;
    const int lane = tid & 63;
    const int cl = lane & 7;
    const int h = lane >> 3;
    const int c = 8 * w + cl;

    // 16 Wk values per lane: rows [16h, 16h+16), column c
    float wk0  = Wk[(size_t)(16*h + 0)*64 + c],  wk1  = Wk[(size_t)(16*h + 1)*64 + c];
    float wk2  = Wk[(size_t)(16*h + 2)*64 + c],  wk3  = Wk[(size_t)(16*h + 3)*64 + c];
    float wk4  = Wk[(size_t)(16*h + 4)*64 + c],  wk5  = Wk[(size_t)(16*h + 5)*64 + c];
    float wk6  = Wk[(size_t)(16*h + 6)*64 + c],  wk7  = Wk[(size_t)(16*h + 7)*64 + c];
    float wk8  = Wk[(size_t)(16*h + 8)*64 + c],  wk9  = Wk[(size_t)(16*h + 9)*64 + c];
    float wk10 = Wk[(size_t)(16*h +10)*64 + c],  wk11 = Wk[(size_t)(16*h +11)*64 + c];
    float wk12 = Wk[(size_t)(16*h +12)*64 + c],  wk13 = Wk[(size_t)(16*h +13)*64 + c];
    float wk14 = Wk[(size_t)(16*h +14)*64 + c],  wk15 = Wk[(size_t)(16*h +15)*64 + c];
    pin(wk0); pin(wk1); pin(wk2); pin(wk3); pin(wk4); pin(wk5); pin(wk6); pin(wk7);
    pin(wk8); pin(wk9); pin(wk10); pin(wk11); pin(wk12); pin(wk13); pin(wk14); pin(wk15);

    // q'_c = bq[c] + bk[c] + hf[b] @ Wq[:,c]   (redundant across h-groups; no barrier)
    float qc = bq[c] + bk[c];
    {
        const float4* hf4 = (const float4*)(hf + (size_t)b * 64);
        #pragma unroll
        for (int k4 = 0; k4 < 16; k4++) {
            const float4 hv = hf4[k4];
            qc = fmaf(hv.x, Wq[(4 * k4 + 0) * 64 + c], qc);
            qc = fmaf(hv.y, Wq[(4 * k4 + 1) * 64 + c], qc);
            qc = fmaf(hv.z, Wq[(4 * k4 + 2) * 64 + c], qc);
            qc = fmaf(hv.w, Wq[(4 * k4 + 3) * 64 + c], qc);
        }
    }
    const float wec = We[c];

    for (int t = 0; t < TT; t++) {
        const float4* orow4 = (const float4*)(outb + ((size_t)b * TT + t) * 128);
        const float4 o0 = orow4[4 * h + 0];
        const float4 o1 = orow4[4 * h + 1];
        const float4 o2 = orow4[4 * h + 2];
        const float4 o3 = orow4[4 * h + 3];
        float a0 = 0.f, a1 = 0.f;
        a0 = fmaf(o0.x, wk0,  a0); a1 = fmaf(o0.y, wk1,  a1);
        a0 = fmaf(o0.z, wk2,  a0); a1 = fmaf(o0.w, wk3,  a1);
        a0 = fmaf(o1.x, wk4,  a0); a1 = fmaf(o1.y, wk5,  a1);
        a0 = fmaf(o1.z, wk6,  a0); a1 = fmaf(o1.w, wk7,  a1);
        a0 = fmaf(o2.x, wk8,  a0); a1 = fmaf(o2.y, wk9,  a1);
        a0 = fmaf(o2.z, wk10, a0); a1 = fmaf(o2.w, wk11, a1);
        a0 = fmaf(o3.x, wk12, a0); a1 = fmaf(o3.y, wk13, a1);
        a0 = fmaf(o3.z, wk14, a0); a1 = fmaf(o3.w, wk15, a1);
        float key = a0 + a1;
        key += __shfl_xor(key, 8);
        key += __shfl_xor(key, 16);
        key += __shfl_xor(key, 32);            // full 128-long dot for column c
        float v = ftanh(key + qc) * wec;       // per-column energy term
        v += __shfl_xor(v, 1);
        v += __shfl_xor(v, 2);
        v += __shfl_xor(v, 4);                 // sum over this wave's 8 columns
        if (lane == 0) epart[w][t] = v;
    }
    __syncthreads();
    if (w == 0) {
        const float bev = be[0];
        for (int t = lane; t < TT; t += 64) {
            float e = epart[0][t] + epart[1][t] + epart[2][t] + epart[3][t]
                    + epart[4][t] + epart[5][t] + epart[6][t] + epart[7][t] + bev;
            if (ids[(size_t)b * TT + t] == 0) e -= 1e9f;
            e_lds[t] = e;
        }
        float m = -1e30f;
        for (int t = lane; t < TT; t += 64) m = fmaxf(m, e_lds[t]);
        #pragma unroll
        for (int off = 32; off > 0; off >>= 1) m = fmaxf(m, __shfl_xor(m, off));
        float ssum = 0.f;
        for (int t = lane; t < TT; t += 64) { const float v = __expf(e_lds[t] - m); e_lds[t] = v; ssum += v; }
        #pragma unroll
        for (int off = 32; off > 0; off >>= 1) ssum += __shfl_xor(ssum, off);
        const float inv = 1.f / ssum;
        for (int t = lane; t < TT; t += 64) e_lds[t] *= inv;
    }
    __syncthreads();
    // context: wave w covers t ≡ w (mod 8); lanes cover 128 cols in two halves
    float c0 = 0.f, c1 = 0.f;
    for (int t = w; t < TT; t += 8) {
        const float* orow = outb + ((size_t)b * TT + t) * 128;
        const float wt = e_lds[t];
        c0 = fmaf(wt, orow[lane], c0);
        c1 = fmaf(wt, orow[64 + lane], c1);
    }
    part[w][lane] = c0;
    part[w][64 + lane] = c1;
    __syncthreads();
    if (tid < 128) {
        float s = part[0][tid] + part[1][tid] + part[2][tid] + part[3][tid]
                + part[4][tid] + part[5][tid] + part[6][tid] + part[7][tid];
        ctx[(size_t)b * 128 + tid] = s;
    }
}

// ---------------- (fallback) GRU 3-wave kernel, recompute-gx variant ----------------
template<bool USE_EMBW>
__global__ __launch_bounds__(192, 2) void gru_kernel(
    const int* __restrict__ ids,
    const float* __restrict__ embW_f, const float* __restrict__ embW_b,
    const float* __restrict__ emb,
    const float* __restrict__ Wx_f, const float* __restrict__ bi_f,
    const float* __restrict__ Wx_b, const float* __restrict__ bi_b,
    const float* __restrict__ Wh_f, const float* __restrict__ br_f,
    const float* __restrict__ Wh_b, const float* __restrict__ br_b,
    float* __restrict__ outb, float* __restrict__ hf_out)
{
    constexpr int R = 4;
    __shared__ float h_lds[R][64];
    __shared__ float rg_lds[R][64];
    __shared__ float hh_lds[R][64];
    __shared__ int ids_lds[R * TT];
    const int tid = threadIdx.x;
    const int w = tid >> 6;
    const int j = tid & 63;
    const int dir = blockIdx.y;
    const int b0 = blockIdx.x * R;
    const float* embW = dir ? embW_b : embW_f;
    const float* Wh   = dir ? Wh_b : Wh_f;
    const float* br   = dir ? br_b : br_f;
    const float* Wx   = dir ? Wx_b : Wx_f;
    const float* bi   = dir ? bi_b : bi_f;
    const int c = w * 64 + j;

    float whc[64];
    #pragma unroll
    for (int k = 0; k < 64; k++) whc[k] = Wh[k * 192 + c];
    const float brc = br[c];
    float wxc[EE];
    float bic = 0.f;
    if (!USE_EMBW) {
        #pragma unroll
        for (int k = 0; k < EE; k++) wxc[k] = Wx[k * 192 + c];
        bic = bi[c];
    }
    for (int i = tid; i < R * TT; i += 192) ids_lds[i] = ids[(size_t)b0 * TT + i];
    if (w == 0) {
        #pragma unroll
        for (int r = 0; r < R; r++) h_lds[r][j] = 0.f;
    }
    __syncthreads();

    for (int s = 0; s < TT; s++) {
        const int t = dir ? (TT - 1 - s) : s;
        int idv[R];
        float gxv[R], accv[R];
        #pragma unroll
        for (int r = 0; r < R; r++) idv[r] = ids_lds[r * TT + t];
        if (USE_EMBW) {
            #pragma unroll
            for (int r = 0; r < R; r++) gxv[r] = embW[(size_t)idv[r] * 192 + c];
        } else {
            #pragma unroll
            for (int r = 0; r < R; r++) {
                float acc = bic;
                const float* er = emb + (size_t)idv[r] * EE;
                #pragma unroll
                for (int k = 0; k < EE; k++) acc = fmaf(er[k], wxc[k], acc);
                gxv[r] = acc;
            }
        }
        #pragma unroll
        for (int r = 0; r < R; r++) {
            float acc = brc;
            const float4* h4 = (const float4*)(&h_lds[r][0]);
            #pragma unroll
            for (int k4 = 0; k4 < 16; k4++) {
                const float4 hv = h4[k4];
                acc = fmaf(hv.x, whc[4 * k4 + 0], acc);
                acc = fmaf(hv.y, whc[4 * k4 + 1], acc);
                acc = fmaf(hv.z, whc[4 * k4 + 2], acc);
                acc = fmaf(hv.w, whc[4 * k4 + 3], acc);
            }
            accv[r] = acc;
        }
        float zg[R] = {};
        if (w == 1) {
            #pragma unroll
            for (int r = 0; r < R; r++) rg_lds[r][j] = fsig(gxv[r] + accv[r]);
        } else if (w == 0) {
            #pragma unroll
            for (int r = 0; r < R; r++) zg[r] = fsig(gxv[r] + accv[r]);
        }
        __syncthreads();
        if (w == 2) {
            #pragma unroll
            for (int r = 0; r < R; r++)
                hh_lds[r][j] = ftanh(gxv[r] + rg_lds[r][j] * accv[r]);
        }
        __syncthreads();
        if (w == 0) {
            #pragma unroll
            for (int r = 0; r < R; r++) {
                const float hold = h_lds[r][j];
                float hnew = hold;
                if (idv[r] != 0) {
                    const float hh = hh_lds[r][j];
                    hnew = zg[r] * hold + (1.f - zg[r]) * hh;
                }
                h_lds[r][j] = hnew;
                outb[((size_t)(b0 + r) * TT + t) * 128 + dir * 64 + j] = hnew;
            }
        }
        __syncthreads();
    }
    if (dir == 0 && w == 0) {
        #pragma unroll
        for (int r = 0; r < R; r++) hf_out[(size_t)(b0 + r) * 64 + j] = h_lds[r][j];
    }
}

extern "C" void kernel_launch(void* const* d_in, const int* in_sizes, int n_in,
                              void* d_out, int out_size, void* d_ws, size_t ws_size,
                              hipStream_t stream) {
    const int*   ids  = (const int*)d_in[0];
    const float* emb  = (const float*)d_in[1];
    const float* Wx_f = (const float*)d_in[2];
    const float* Wh_f = (const float*)d_in[3];
    const float* bi_f = (const float*)d_in[4];
    const float* br_f = (const float*)d_in[5];
    const float* Wx_b = (const float*)d_in[6];
    const float* Wh_b = (const float*)d_in[7];
    const float* bi_b = (const float*)d_in[8];
    const float* br_b = (const float*)d_in[9];
    const float* Wk   = (const float*)d_in[10];
    const float* bk   = (const float*)d_in[11];
    const float* Wq   = (const float*)d_in[12];
    const float* bq   = (const float*)d_in[13];
    const float* We   = (const float*)d_in[14];
    const float* be   = (const float*)d_in[15];
    float* ctx = (float*)d_out;

    float* ws = (float*)d_ws;
    const size_t embw_elems = (size_t)VV * 192;
    const size_t out_elems  = (size_t)BB * TT * 128;
    const size_t hf_elems   = (size_t)BB * 64;
    const size_t need_embw  = (2 * embw_elems + out_elems + hf_elems) * sizeof(float);
    const bool use_embw = (ws_size >= need_embw);

    float *embW_f = nullptr, *embW_b = nullptr, *outb, *hf;
    if (use_embw) {
        embW_f = ws;
        embW_b = embW_f + embw_elems;
        outb   = embW_b + embw_elems;
        hf     = outb + out_elems;
    } else {
        outb = ws;
        hf   = outb + out_elems;
    }

    if (use_embw) {
        embw_kernel<<<dim3(VV / 32, 2), 256, 0, stream>>>(
            emb, Wx_f, bi_f, Wx_b, bi_b, embW_f, embW_b);
        gru4_kernel<<<dim3(BB, 2), 64, 0, stream>>>(
            ids, embW_f, embW_b, Wh_f, br_f, Wh_b, br_b, outb, hf);
    } else {
        gru_kernel<false><<<dim3(BB / 4, 2), 192, 0, stream>>>(
            ids, embW_f, embW_b, emb, Wx_f, bi_f, Wx_b, bi_b,
            Wh_f, br_f, Wh_b, br_b, outb, hf);
    }
    attn6_kernel<<<BB, 512, 0, stream>>>(ids, outb, hf, Wk, bk, Wq, bq, We, be, ctx);
}

// Round 7
// 313.674 us; speedup vs baseline: 1.6210x; 1.6210x over previous
//
#include <hip/hip_runtime.h>
#include <hip/hip_bf16.h>

#define VV 100000
#define EE 50
#define HH 64
#define BB 1024
#define TT 200
// 3H = 192

typedef float v4f __attribute__((ext_vector_type(4)));
typedef float f32x4 __attribute__((ext_vector_type(4)));
typedef short bf16x8 __attribute__((ext_vector_type(8)));

__device__ __forceinline__ float fsig(float x) {
    return 1.f / (1.f + __expf(-x));
}
__device__ __forceinline__ float ftanh(float x) {
    float e = __expf(2.f * x);
    return 1.f - 2.f / (e + 1.f);
}
// fp32 -> bf16 round-to-nearest-even (values are tame: no NaN/Inf handling needed)
__device__ __forceinline__ short f2bf(float f) {
    union { float f; unsigned u; } v; v.f = f;
    unsigned r = v.u + 0x7FFFu + ((v.u >> 16) & 1u);
    return (short)(r >> 16);
}

// ---------------- Kernel A: embW[v][c] = emb[v][:] @ Wx[:,c] + bi[c]  (both dirs via blockIdx.y) ----------------
__global__ __launch_bounds__(256) void embw_kernel(
    const float* __restrict__ emb,
    const float* __restrict__ Wx_f, const float* __restrict__ bi_f,
    const float* __restrict__ Wx_b, const float* __restrict__ bi_b,
    float* __restrict__ embW_f, float* __restrict__ embW_b)
{
    const float* Wx = blockIdx.y ? Wx_b : Wx_f;
    const float* bi = blockIdx.y ? bi_b : bi_f;
    float* embW     = blockIdx.y ? embW_b : embW_f;
    __shared__ float wx_lds[EE * 192];
    __shared__ float emb_lds[32 * EE];
    const int tid = threadIdx.x;
    const int v0 = blockIdx.x * 32;
    for (int i = tid; i < EE * 192; i += 256) wx_lds[i] = Wx[i];
    for (int i = tid; i < 32 * EE; i += 256) emb_lds[i] = emb[(size_t)v0 * EE + i];
    __syncthreads();
    const int cg = tid & 63;
    const int rg = tid >> 6;
    float acc[8][3];
    #pragma unroll
    for (int i = 0; i < 8; i++) {
        acc[i][0] = bi[cg];
        acc[i][1] = bi[cg + 64];
        acc[i][2] = bi[cg + 128];
    }
    for (int k = 0; k < EE; k++) {
        const float wx0 = wx_lds[k * 192 + cg];
        const float wx1 = wx_lds[k * 192 + cg + 64];
        const float wx2 = wx_lds[k * 192 + cg + 128];
        #pragma unroll
        for (int i = 0; i < 8; i++) {
            const float ev = emb_lds[(rg * 8 + i) * EE + k];
            acc[i][0] = fmaf(ev, wx0, acc[i][0]);
            acc[i][1] = fmaf(ev, wx1, acc[i][1]);
            acc[i][2] = fmaf(ev, wx2, acc[i][2]);
        }
    }
    #pragma unroll
    for (int i = 0; i < 8; i++) {
        const size_t row = (size_t)(v0 + rg * 8 + i) * 192;
        embW[row + cg]       = acc[i][0];
        embW[row + cg + 64]  = acc[i][1];
        embW[row + cg + 128] = acc[i][2];
    }
}

// ---------------- Kernel B v4: one wave per (sequence, direction); opaque register weights ----
__device__ __forceinline__ void opaque(v4f& x) {
    float a = x[0], b = x[1], c = x[2], d = x[3];
    asm volatile("" : "+v"(a), "+v"(b), "+v"(c), "+v"(d));
    x[0] = a; x[1] = b; x[2] = c; x[3] = d;
}
#define DECL_W(i) \
    v4f wz##i = {Wh[(4*i+0)*192+j],     Wh[(4*i+1)*192+j],     Wh[(4*i+2)*192+j],     Wh[(4*i+3)*192+j]};     \
    v4f wr##i = {Wh[(4*i+0)*192+64+j],  Wh[(4*i+1)*192+64+j],  Wh[(4*i+2)*192+64+j],  Wh[(4*i+3)*192+64+j]};  \
    v4f wn##i = {Wh[(4*i+0)*192+128+j], Wh[(4*i+1)*192+128+j], Wh[(4*i+2)*192+128+j], Wh[(4*i+3)*192+128+j]}; \
    opaque(wz##i); opaque(wr##i); opaque(wn##i);

#define GSTEP(i) { const v4f hv = h4[i]; \
    aZ = __builtin_elementwise_fma(hv, wz##i, aZ); \
    aR = __builtin_elementwise_fma(hv, wr##i, aR); \
    aN = __builtin_elementwise_fma(hv, wn##i, aN); }

__global__ __launch_bounds__(64, 2) void gru4_kernel(
    const int* __restrict__ ids,
    const float* __restrict__ embW_f, const float* __restrict__ embW_b,
    const float* __restrict__ Wh_f, const float* __restrict__ br_f,
    const float* __restrict__ Wh_b, const float* __restrict__ br_b,
    float* __restrict__ outb,     // [B, T, 128]
    float* __restrict__ hf_out)   // [B, 64]
{
    const int j   = threadIdx.x;
    const int b   = blockIdx.x;
    const int dir = blockIdx.y;
    const float* eW = dir ? embW_b : embW_f;
    const float* Wh = dir ? Wh_b : Wh_f;
    const float* br = dir ? br_b : br_f;

    DECL_W(0)  DECL_W(1)  DECL_W(2)  DECL_W(3)
    DECL_W(4)  DECL_W(5)  DECL_W(6)  DECL_W(7)
    DECL_W(8)  DECL_W(9)  DECL_W(10) DECL_W(11)
    DECL_W(12) DECL_W(13) DECL_W(14) DECL_W(15)
    const float brz = br[j], brr = br[64 + j], brn = br[128 + j];

    __shared__ __align__(16) float h_lds[64];
    __shared__ int ids_lds[TT];
    for (int i = j; i < TT; i += 64) ids_lds[i] = ids[(size_t)b * TT + i];
    h_lds[j] = 0.f;
    float hj = 0.f;
    __syncthreads();   // one-time; none inside the step loop

    const int t0 = dir ? (TT - 1) : 0;
    const int dt = dir ? -1 : 1;

    int   id0 = ids_lds[t0];
    float gz0 = eW[(size_t)id0 * 192 + j];
    float gr0 = eW[(size_t)id0 * 192 + 64 + j];
    float gn0 = eW[(size_t)id0 * 192 + 128 + j];
    int   id1 = ids_lds[t0 + dt];
    float gz1 = eW[(size_t)id1 * 192 + j];
    float gr1 = eW[(size_t)id1 * 192 + 64 + j];
    float gn1 = eW[(size_t)id1 * 192 + 128 + j];

    float* obase = outb + (size_t)b * TT * 128 + dir * 64 + j;

    for (int s = 0; s < TT; s++) {
        const int t = t0 + s * dt;
        int id2 = 0; float gz2 = 0.f, gr2 = 0.f, gn2 = 0.f;
        if (s + 2 < TT) {
            id2 = ids_lds[t + 2 * dt];
            gz2 = eW[(size_t)id2 * 192 + j];
            gr2 = eW[(size_t)id2 * 192 + 64 + j];
            gn2 = eW[(size_t)id2 * 192 + 128 + j];
        }
        v4f aZ = {brz, 0.f, 0.f, 0.f};
        v4f aR = {brr, 0.f, 0.f, 0.f};
        v4f aN = {brn, 0.f, 0.f, 0.f};
        const v4f* h4 = (const v4f*)h_lds;
        GSTEP(0)  GSTEP(1)  GSTEP(2)  GSTEP(3)
        GSTEP(4)  GSTEP(5)  GSTEP(6)  GSTEP(7)
        GSTEP(8)  GSTEP(9)  GSTEP(10) GSTEP(11)
        GSTEP(12) GSTEP(13) GSTEP(14) GSTEP(15)
        const float az = (aZ[0] + aZ[1]) + (aZ[2] + aZ[3]);
        const float ar = (aR[0] + aR[1]) + (aR[2] + aR[3]);
        const float an = (aN[0] + aN[1]) + (aN[2] + aN[3]);
        const float z  = fsig(gz0 + az);
        const float r  = fsig(gr0 + ar);
        const float hh = ftanh(gn0 + r * an);
        float hnew = z * hj + (1.f - z) * hh;
        hnew = (id0 != 0) ? hnew : hj;
        hj = hnew;
        h_lds[j] = hj;
        obase[(size_t)t * 128] = hj;
        id0 = id1; gz0 = gz1; gr0 = gr1; gn0 = gn1;
        id1 = id2; gz1 = gz2; gr1 = gr2; gn1 = gn2;
    }
    if (dir == 0) hf_out[(size_t)b * 64 + j] = hj;
}

// ---------------- Kernel C v7: MFMA keys GEMM ----------------
// One block per b, 256 thr = 4 waves. keys[t, c] = out[b,t,:128] @ Wk[:, c].
// mfma_f32_16x16x32_bf16: A row = lane&15 (=t within tile), k = 8*(lane>>4)+j;
// B col = lane&15 (=c within n-tile), same k map; C/D col=lane&15, row=4*(lane>>4)+reg (m89-verified).
// Wk staged once into LDS, pre-swizzled to B-fragment order -> one ds_read_b128 per MFMA.
#define NTILE 13   // ceil(200/16)

__global__ __launch_bounds__(256) void attn7_kernel(
    const int* __restrict__ ids,
    const float* __restrict__ outb,   // [B,T,128] fp32
    const float* __restrict__ hf,     // [B,64]
    const float* __restrict__ Wk, const float* __restrict__ bk,
    const float* __restrict__ Wq, const float* __restrict__ bq,
    const float* __restrict__ We, const float* __restrict__ be,
    float* __restrict__ ctx)          // [B,128]
{
    __shared__ __align__(16) short wk_sw[1024 * 8];  // [slot][j]; slot = ks*256 + lhi*64 + nt*16 + l15
    __shared__ float q_lds[64];
    __shared__ float we_lds[64];
    __shared__ float e_lds[TT];
    __shared__ float part[4][128];
    const int b = blockIdx.x;
    const int tid = threadIdx.x;
    const int w = tid >> 6;
    const int lane = tid & 63;
    const int l15 = lane & 15;
    const int lhi = lane >> 4;

    // Stage Wk (fp32 -> bf16) into fragment-ordered LDS. Each thread fills 4 slots of 8 values.
    #pragma unroll
    for (int i = 0; i < 4; i++) {
        const int slot = tid + 256 * i;
        const int s_l15 = slot & 15;
        const int s_nt  = (slot >> 4) & 3;
        const int s_lhi = (slot >> 6) & 3;
        const int s_ks  = slot >> 8;
        const int kbase = 32 * s_ks + 8 * s_lhi;
        const int col   = 16 * s_nt + s_l15;
        bf16x8 v;
        #pragma unroll
        for (int jj = 0; jj < 8; jj++) v[jj] = f2bf(Wk[(size_t)(kbase + jj) * 64 + col]);
        *(bf16x8*)&wk_sw[slot * 8] = v;
    }
    // q[c] = bq[c] + hf[b] @ Wq[:,c] (wave 0; coalesced column reads)
    if (tid < 64) {
        float qc = bq[tid];
        const float* hfb = hf + (size_t)b * 64;
        for (int k = 0; k < 64; k++) qc = fmaf(hfb[k], Wq[k * 64 + tid], qc);
        q_lds[tid] = qc;
        we_lds[tid] = We[tid];
    }
    __syncthreads();

    // keys + energy, 16-row tiles round-robined over the 4 waves
    for (int tile = w; tile < NTILE; tile += 4) {
        const int t0 = tile * 16;
        const int t = t0 + l15;
        f32x4 acc[4];
        #pragma unroll
        for (int nt = 0; nt < 4; nt++) { acc[nt][0] = 0.f; acc[nt][1] = 0.f; acc[nt][2] = 0.f; acc[nt][3] = 0.f; }
        #pragma unroll
        for (int ks = 0; ks < 4; ks++) {
            bf16x8 a;
            if (t < TT) {
                const float* p = outb + ((size_t)b * TT + t) * 128 + 32 * ks + 8 * lhi;
                const float4 lo = *(const float4*)p;
                const float4 hi = *(const float4*)(p + 4);
                a[0] = f2bf(lo.x); a[1] = f2bf(lo.y); a[2] = f2bf(lo.z); a[3] = f2bf(lo.w);
                a[4] = f2bf(hi.x); a[5] = f2bf(hi.y); a[6] = f2bf(hi.z); a[7] = f2bf(hi.w);
            } else {
                #pragma unroll
                for (int jj = 0; jj < 8; jj++) a[jj] = 0;
            }
            #pragma unroll
            for (int nt = 0; nt < 4; nt++) {
                const bf16x8 bf = *(const bf16x8*)&wk_sw[(ks * 256 + lhi * 64 + nt * 16 + l15) * 8];
                acc[nt] = __builtin_amdgcn_mfma_f32_16x16x32_bf16(a, bf, acc[nt], 0, 0, 0);
            }
        }
        // energy partials: ep[r] = sum_c We[c] * tanh(keys[t0+4*lhi+r][c] + q[c]); c spread over l15 x nt
        float ep0 = 0.f, ep1 = 0.f, ep2 = 0.f, ep3 = 0.f;
        #pragma unroll
        for (int nt = 0; nt < 4; nt++) {
            const int c = 16 * nt + l15;
            const float qn = q_lds[c];
            const float wen = we_lds[c];
            ep0 = fmaf(wen, ftanh(acc[nt][0] + qn), ep0);
            ep1 = fmaf(wen, ftanh(acc[nt][1] + qn), ep1);
            ep2 = fmaf(wen, ftanh(acc[nt][2] + qn), ep2);
            ep3 = fmaf(wen, ftanh(acc[nt][3] + qn), ep3);
        }
        #pragma unroll
        for (int off = 1; off < 16; off <<= 1) {
            ep0 += __shfl_xor(ep0, off);
            ep1 += __shfl_xor(ep1, off);
            ep2 += __shfl_xor(ep2, off);
            ep3 += __shfl_xor(ep3, off);
        }
        if (l15 == 0) {
            const int rbase = t0 + 4 * lhi;
            if (rbase + 0 < TT) e_lds[rbase + 0] = ep0;
            if (rbase + 1 < TT) e_lds[rbase + 1] = ep1;
            if (rbase + 2 < TT) e_lds[rbase + 2] = ep2;
            if (rbase + 3 < TT) e_lds[rbase + 3] = ep3;
        }
    }
    __syncthreads();
    // softmax over t (wave 0)
    if (w == 0) {
        const float bev = be[0];
        for (int t = lane; t < TT; t += 64) {
            float e = e_lds[t] + bev;
            if (ids[(size_t)b * TT + t] == 0) e -= 1e9f;
            e_lds[t] = e;
        }
        float m = -1e30f;
        for (int t = lane; t < TT; t += 64) m = fmaxf(m, e_lds[t]);
        #pragma unroll
        for (int off = 32; off > 0; off >>= 1) m = fmaxf(m, __shfl_xor(m, off));
        float ssum = 0.f;
        for (int t = lane; t < TT; t += 64) { const float v = __expf(e_lds[t] - m); e_lds[t] = v; ssum += v; }
        #pragma unroll
        for (int off = 32; off > 0; off >>= 1) ssum += __shfl_xor(ssum, off);
        const float inv = 1.f / ssum;
        for (int t = lane; t < TT; t += 64) e_lds[t] *= inv;
    }
    __syncthreads();
    // context (fp32): wave w covers t ≡ w (mod 4)
    float c0 = 0.f, c1 = 0.f;
    for (int t = w; t < TT; t += 4) {
        const float* orow = outb + ((size_t)b * TT + t) * 128;
        const float wt = e_lds[t];
        c0 = fmaf(wt, orow[lane], c0);
        c1 = fmaf(wt, orow[64 + lane], c1);
    }
    part[w][lane] = c0;
    part[w][64 + lane] = c1;
    __syncthreads();
    if (tid < 128)
        ctx[(size_t)b * 128 + tid] = part[0][tid] + part[1][tid] + part[2][tid] + part[3][tid];
}

// ---------------- (fallback) GRU 3-wave kernel, recompute-gx variant ----------------
template<bool USE_EMBW>
__global__ __launch_bounds__(192, 2) void gru_kernel(
    const int* __restrict__ ids,
    const float* __restrict__ embW_f, const float* __restrict__ embW_b,
    const float* __restrict__ emb,
    const float* __restrict__ Wx_f, const float* __restrict__ bi_f,
    const float* __restrict__ Wx_b, const float* __restrict__ bi_b,
    const float* __restrict__ Wh_f, const float* __restrict__ br_f,
    const float* __restrict__ Wh_b, const float* __restrict__ br_b,
    float* __restrict__ outb, float* __restrict__ hf_out)
{
    constexpr int R = 4;
    __shared__ float h_lds[R][64];
    __shared__ float rg_lds[R][64];
    __shared__ float hh_lds[R][64];
    __shared__ int ids_lds[R * TT];
    const int tid = threadIdx.x;
    const int w = tid >> 6;
    const int j = tid & 63;
    const int dir = blockIdx.y;
    const int b0 = blockIdx.x * R;
    const float* embW = dir ? embW_b : embW_f;
    const float* Wh   = dir ? Wh_b : Wh_f;
    const float* br   = dir ? br_b : br_f;
    const float* Wx   = dir ? Wx_b : Wx_f;
    const float* bi   = dir ? bi_b : bi_f;
    const int c = w * 64 + j;

    float whc[64];
    #pragma unroll
    for (int k = 0; k < 64; k++) whc[k] = Wh[k * 192 + c];
    const float brc = br[c];
    float wxc[EE];
    float bic = 0.f;
    if (!USE_EMBW) {
        #pragma unroll
        for (int k = 0; k < EE; k++) wxc[k] = Wx[k * 192 + c];
        bic = bi[c];
    }
    for (int i = tid; i < R * TT; i += 192) ids_lds[i] = ids[(size_t)b0 * TT + i];
    if (w == 0) {
        #pragma unroll
        for (int r = 0; r < R; r++) h_lds[r][j] = 0.f;
    }
    __syncthreads();

    for (int s = 0; s < TT; s++) {
        const int t = dir ? (TT - 1 - s) : s;
        int idv[R];
        float gxv[R], accv[R];
        #pragma unroll
        for (int r = 0; r < R; r++) idv[r] = ids_lds[r * TT + t];
        if (USE_EMBW) {
            #pragma unroll
            for (int r = 0; r < R; r++) gxv[r] = embW[(size_t)idv[r] * 192 + c];
        } else {
            #pragma unroll
            for (int r = 0; r < R; r++) {
                float acc = bic;
                const float* er = emb + (size_t)idv[r] * EE;
                #pragma unroll
                for (int k = 0; k < EE; k++) acc = fmaf(er[k], wxc[k], acc);
                gxv[r] = acc;
            }
        }
        #pragma unroll
        for (int r = 0; r < R; r++) {
            float acc = brc;
            const float4* h4 = (const float4*)(&h_lds[r][0]);
            #pragma unroll
            for (int k4 = 0; k4 < 16; k4++) {
                const float4 hv = h4[k4];
                acc = fmaf(hv.x, whc[4 * k4 + 0], acc);
                acc = fmaf(hv.y, whc[4 * k4 + 1], acc);
                acc = fmaf(hv.z, whc[4 * k4 + 2], acc);
                acc = fmaf(hv.w, whc[4 * k4 + 3], acc);
            }
            accv[r] = acc;
        }
        float zg[R] = {};
        if (w == 1) {
            #pragma unroll
            for (int r = 0; r < R; r++) rg_lds[r][j] = fsig(gxv[r] + accv[r]);
        } else if (w == 0) {
            #pragma unroll
            for (int r = 0; r < R; r++) zg[r] = fsig(gxv[r] + accv[r]);
        }
        __syncthreads();
        if (w == 2) {
            #pragma unroll
            for (int r = 0; r < R; r++)
                hh_lds[r][j] = ftanh(gxv[r] + rg_lds[r][j] * accv[r]);
        }
        __syncthreads();
        if (w == 0) {
            #pragma unroll
            for (int r = 0; r < R; r++) {
                const float hold = h_lds[r][j];
                float hnew = hold;
                if (idv[r] != 0) {
                    const float hh = hh_lds[r][j];
                    hnew = zg[r] * hold + (1.f - zg[r]) * hh;
                }
                h_lds[r][j] = hnew;
                outb[((size_t)(b0 + r) * TT + t) * 128 + dir * 64 + j] = hnew;
            }
        }
        __syncthreads();
    }
    if (dir == 0 && w == 0) {
        #pragma unroll
        for (int r = 0; r < R; r++) hf_out[(size_t)(b0 + r) * 64 + j] = h_lds[r][j];
    }
}

extern "C" void kernel_launch(void* const* d_in, const int* in_sizes, int n_in,
                              void* d_out, int out_size, void* d_ws, size_t ws_size,
                              hipStream_t stream) {
    const int*   ids  = (const int*)d_in[0];
    const float* emb  = (const float*)d_in[1];
    const float* Wx_f = (const float*)d_in[2];
    const float* Wh_f = (const float*)d_in[3];
    const float* bi_f = (const float*)d_in[4];
    const float* br_f = (const float*)d_in[5];
    const float* Wx_b = (const float*)d_in[6];
    const float* Wh_b = (const float*)d_in[7];
    const float* bi_b = (const float*)d_in[8];
    const float* br_b = (const float*)d_in[9];
    const float* Wk   = (const float*)d_in[10];
    const float* bk   = (const float*)d_in[11];
    const float* Wq   = (const float*)d_in[12];
    const float* bq   = (const float*)d_in[13];
    const float* We   = (const float*)d_in[14];
    const float* be   = (const float*)d_in[15];
    float* ctx = (float*)d_out;

    float* ws = (float*)d_ws;
    const size_t embw_elems = (size_t)VV * 192;
    const size_t out_elems  = (size_t)BB * TT * 128;
    const size_t hf_elems   = (size_t)BB * 64;
    const size_t need_embw  = (2 * embw_elems + out_elems + hf_elems) * sizeof(float);
    const bool use_embw = (ws_size >= need_embw);

    float *embW_f = nullptr, *embW_b = nullptr, *outb, *hf;
    if (use_embw) {
        embW_f = ws;
        embW_b = embW_f + embw_elems;
        outb   = embW_b + embw_elems;
        hf     = outb + out_elems;
    } else {
        outb = ws;
        hf   = outb + out_elems;
    }

    if (use_embw) {
        embw_kernel<<<dim3(VV / 32, 2), 256, 0, stream>>>(
            emb, Wx_f, bi_f, Wx_b, bi_b, embW_f, embW_b);
        gru4_kernel<<<dim3(BB, 2), 64, 0, stream>>>(
            ids, embW_f, embW_b, Wh_f, br_f, Wh_b, br_b, outb, hf);
    } else {
        gru_kernel<false><<<dim3(BB / 4, 2), 192, 0, stream>>>(
            ids, embW_f, embW_b, emb, Wx_f, bi_f, Wx_b, bi_b,
            Wh_f, br_f, Wh_b, br_b, outb, hf);
    }
    attn7_kernel<<<BB, 256, 0, stream>>>(ids, outb, hf, Wk, bk, Wq, bq, We, be, ctx);
}

// Round 8
// 313.481 us; speedup vs baseline: 1.6220x; 1.0006x over previous
//
#include <hip/hip_runtime.h>
#include <hip/hip_bf16.h>

#define VV 100000
#define EE 50
#define HH 64
#define BB 1024
#define TT 200
// 3H = 192

typedef float v4f __attribute__((ext_vector_type(4)));
typedef float f32x4 __attribute__((ext_vector_type(4)));
typedef short bf16x8 __attribute__((ext_vector_type(8)));

__device__ __forceinline__ float fsig(float x) {
    return 1.f / (1.f + __expf(-x));
}
__device__ __forceinline__ float ftanh(float x) {
    float e = __expf(2.f * x);
    return 1.f - 2.f / (e + 1.f);
}
// fp32 -> bf16 round-to-nearest-even (values are tame: no NaN/Inf handling needed)
__device__ __forceinline__ short f2bf(float f) {
    union { float f; unsigned u; } v; v.f = f;
    unsigned r = v.u + 0x7FFFu + ((v.u >> 16) & 1u);
    return (short)(r >> 16);
}

// ---------------- Kernel A: embW[v][c] = emb[v][:] @ Wx[:,c] + bi[c]  (both dirs via blockIdx.y) ----------------
__global__ __launch_bounds__(256) void embw_kernel(
    const float* __restrict__ emb,
    const float* __restrict__ Wx_f, const float* __restrict__ bi_f,
    const float* __restrict__ Wx_b, const float* __restrict__ bi_b,
    float* __restrict__ embW_f, float* __restrict__ embW_b)
{
    const float* Wx = blockIdx.y ? Wx_b : Wx_f;
    const float* bi = blockIdx.y ? bi_b : bi_f;
    float* embW     = blockIdx.y ? embW_b : embW_f;
    __shared__ float wx_lds[EE * 192];
    __shared__ float emb_lds[32 * EE];
    const int tid = threadIdx.x;
    const int v0 = blockIdx.x * 32;
    for (int i = tid; i < EE * 192; i += 256) wx_lds[i] = Wx[i];
    for (int i = tid; i < 32 * EE; i += 256) emb_lds[i] = emb[(size_t)v0 * EE + i];
    __syncthreads();
    const int cg = tid & 63;
    const int rg = tid >> 6;
    float acc[8][3];
    #pragma unroll
    for (int i = 0; i < 8; i++) {
        acc[i][0] = bi[cg];
        acc[i][1] = bi[cg + 64];
        acc[i][2] = bi[cg + 128];
    }
    for (int k = 0; k < EE; k++) {
        const float wx0 = wx_lds[k * 192 + cg];
        const float wx1 = wx_lds[k * 192 + cg + 64];
        const float wx2 = wx_lds[k * 192 + cg + 128];
        #pragma unroll
        for (int i = 0; i < 8; i++) {
            const float ev = emb_lds[(rg * 8 + i) * EE + k];
            acc[i][0] = fmaf(ev, wx0, acc[i][0]);
            acc[i][1] = fmaf(ev, wx1, acc[i][1]);
            acc[i][2] = fmaf(ev, wx2, acc[i][2]);
        }
    }
    #pragma unroll
    for (int i = 0; i < 8; i++) {
        const size_t row = (size_t)(v0 + rg * 8 + i) * 192;
        embW[row + cg]       = acc[i][0];
        embW[row + cg + 64]  = acc[i][1];
        embW[row + cg + 128] = acc[i][2];
    }
}

// ---------------- Kernel B v5: one wave per (sequence, direction); waves_per_eu pinned to 2 ----
// amdgpu_waves_per_eu(2,2): grid is exactly 2 waves/SIMD chip-wide, so cap occupancy there and
// give the RA the full 256-VGPR budget -> 192 weight floats stay resident, zero scratch.
__device__ __forceinline__ void opaque(v4f& x) {
    float a = x[0], b = x[1], c = x[2], d = x[3];
    asm volatile("" : "+v"(a), "+v"(b), "+v"(c), "+v"(d));
    x[0] = a; x[1] = b; x[2] = c; x[3] = d;
}
#define DECL_W(i) \
    v4f wz##i = {Wh[(4*i+0)*192+j],     Wh[(4*i+1)*192+j],     Wh[(4*i+2)*192+j],     Wh[(4*i+3)*192+j]};     \
    v4f wr##i = {Wh[(4*i+0)*192+64+j],  Wh[(4*i+1)*192+64+j],  Wh[(4*i+2)*192+64+j],  Wh[(4*i+3)*192+64+j]};  \
    v4f wn##i = {Wh[(4*i+0)*192+128+j], Wh[(4*i+1)*192+128+j], Wh[(4*i+2)*192+128+j], Wh[(4*i+3)*192+128+j]}; \
    opaque(wz##i); opaque(wr##i); opaque(wn##i);

#define GSTEP(i) { const v4f hv = h4[i]; \
    aZ = __builtin_elementwise_fma(hv, wz##i, aZ); \
    aR = __builtin_elementwise_fma(hv, wr##i, aR); \
    aN = __builtin_elementwise_fma(hv, wn##i, aN); }

__global__ __launch_bounds__(64)
__attribute__((amdgpu_waves_per_eu(2, 2)))
void gru5_kernel(
    const int* __restrict__ ids,
    const float* __restrict__ embW_f, const float* __restrict__ embW_b,
    const float* __restrict__ Wh_f, const float* __restrict__ br_f,
    const float* __restrict__ Wh_b, const float* __restrict__ br_b,
    float* __restrict__ outb,     // [B, T, 128]
    float* __restrict__ hf_out)   // [B, 64]
{
    const int j   = threadIdx.x;
    const int b   = blockIdx.x;
    const int dir = blockIdx.y;
    const float* eW = dir ? embW_b : embW_f;
    const float* Wh = dir ? Wh_b : Wh_f;
    const float* br = dir ? br_b : br_f;

    DECL_W(0)  DECL_W(1)  DECL_W(2)  DECL_W(3)
    DECL_W(4)  DECL_W(5)  DECL_W(6)  DECL_W(7)
    DECL_W(8)  DECL_W(9)  DECL_W(10) DECL_W(11)
    DECL_W(12) DECL_W(13) DECL_W(14) DECL_W(15)
    const float brz = br[j], brr = br[64 + j], brn = br[128 + j];

    __shared__ __align__(16) float h_lds[64];
    __shared__ int ids_lds[TT];
    for (int i = j; i < TT; i += 64) ids_lds[i] = ids[(size_t)b * TT + i];
    h_lds[j] = 0.f;
    float hj = 0.f;
    __syncthreads();   // one-time; none inside the step loop

    const int t0 = dir ? (TT - 1) : 0;
    const int dt = dir ? -1 : 1;

    int   id0 = ids_lds[t0];
    float gz0 = eW[(size_t)id0 * 192 + j];
    float gr0 = eW[(size_t)id0 * 192 + 64 + j];
    float gn0 = eW[(size_t)id0 * 192 + 128 + j];
    int   id1 = ids_lds[t0 + dt];
    float gz1 = eW[(size_t)id1 * 192 + j];
    float gr1 = eW[(size_t)id1 * 192 + 64 + j];
    float gn1 = eW[(size_t)id1 * 192 + 128 + j];

    float* obase = outb + (size_t)b * TT * 128 + dir * 64 + j;

    for (int s = 0; s < TT; s++) {
        const int t = t0 + s * dt;
        int id2 = 0; float gz2 = 0.f, gr2 = 0.f, gn2 = 0.f;
        if (s + 2 < TT) {
            id2 = ids_lds[t + 2 * dt];
            gz2 = eW[(size_t)id2 * 192 + j];
            gr2 = eW[(size_t)id2 * 192 + 64 + j];
            gn2 = eW[(size_t)id2 * 192 + 128 + j];
        }
        v4f aZ = {brz, 0.f, 0.f, 0.f};
        v4f aR = {brr, 0.f, 0.f, 0.f};
        v4f aN = {brn, 0.f, 0.f, 0.f};
        const v4f* h4 = (const v4f*)h_lds;
        GSTEP(0)  GSTEP(1)  GSTEP(2)  GSTEP(3)
        GSTEP(4)  GSTEP(5)  GSTEP(6)  GSTEP(7)
        GSTEP(8)  GSTEP(9)  GSTEP(10) GSTEP(11)
        GSTEP(12) GSTEP(13) GSTEP(14) GSTEP(15)
        const float az = (aZ[0] + aZ[1]) + (aZ[2] + aZ[3]);
        const float ar = (aR[0] + aR[1]) + (aR[2] + aR[3]);
        const float an = (aN[0] + aN[1]) + (aN[2] + aN[3]);
        const float z  = fsig(gz0 + az);
        const float r  = fsig(gr0 + ar);
        const float hh = ftanh(gn0 + r * an);
        float hnew = z * hj + (1.f - z) * hh;
        hnew = (id0 != 0) ? hnew : hj;
        hj = hnew;
        h_lds[j] = hj;
        obase[(size_t)t * 128] = hj;
        id0 = id1; gz0 = gz1; gr0 = gr1; gn0 = gn1;
        id1 = id2; gz1 = gz2; gr1 = gr2; gn1 = gn2;
    }
    if (dir == 0) hf_out[(size_t)b * 64 + j] = hj;
}

// ---------------- Kernel C v7: MFMA keys GEMM ----------------
// One block per b, 256 thr = 4 waves. keys[t, c] = out[b,t,:128] @ Wk[:, c].
// mfma_f32_16x16x32_bf16: A row = lane&15 (=t within tile), k = 8*(lane>>4)+j;
// B col = lane&15 (=c within n-tile), same k map; C/D col=lane&15, row=4*(lane>>4)+reg (m89-verified).
// Wk staged once into LDS, pre-swizzled to B-fragment order -> one ds_read_b128 per MFMA.
#define NTILE 13   // ceil(200/16)

__global__ __launch_bounds__(256) void attn7_kernel(
    const int* __restrict__ ids,
    const float* __restrict__ outb,   // [B,T,128] fp32
    const float* __restrict__ hf,     // [B,64]
    const float* __restrict__ Wk, const float* __restrict__ bk,
    const float* __restrict__ Wq, const float* __restrict__ bq,
    const float* __restrict__ We, const float* __restrict__ be,
    float* __restrict__ ctx)          // [B,128]
{
    __shared__ __align__(16) short wk_sw[1024 * 8];  // [slot][j]; slot = ks*256 + lhi*64 + nt*16 + l15
    __shared__ float q_lds[64];
    __shared__ float we_lds[64];
    __shared__ float e_lds[TT];
    __shared__ float part[4][128];
    const int b = blockIdx.x;
    const int tid = threadIdx.x;
    const int w = tid >> 6;
    const int lane = tid & 63;
    const int l15 = lane & 15;
    const int lhi = lane >> 4;

    // Stage Wk (fp32 -> bf16) into fragment-ordered LDS. Each thread fills 4 slots of 8 values.
    #pragma unroll
    for (int i = 0; i < 4; i++) {
        const int slot = tid + 256 * i;
        const int s_l15 = slot & 15;
        const int s_nt  = (slot >> 4) & 3;
        const int s_lhi = (slot >> 6) & 3;
        const int s_ks  = slot >> 8;
        const int kbase = 32 * s_ks + 8 * s_lhi;
        const int col   = 16 * s_nt + s_l15;
        bf16x8 v;
        #pragma unroll
        for (int jj = 0; jj < 8; jj++) v[jj] = f2bf(Wk[(size_t)(kbase + jj) * 64 + col]);
        *(bf16x8*)&wk_sw[slot * 8] = v;
    }
    // q[c] = bq[c] + hf[b] @ Wq[:,c] (wave 0; coalesced column reads)
    if (tid < 64) {
        float qc = bq[tid];
        const float* hfb = hf + (size_t)b * 64;
        for (int k = 0; k < 64; k++) qc = fmaf(hfb[k], Wq[k * 64 + tid], qc);
        q_lds[tid] = qc;
        we_lds[tid] = We[tid];
    }
    __syncthreads();

    // keys + energy, 16-row tiles round-robined over the 4 waves
    for (int tile = w; tile < NTILE; tile += 4) {
        const int t0 = tile * 16;
        const int t = t0 + l15;
        f32x4 acc[4];
        #pragma unroll
        for (int nt = 0; nt < 4; nt++) { acc[nt][0] = 0.f; acc[nt][1] = 0.f; acc[nt][2] = 0.f; acc[nt][3] = 0.f; }
        #pragma unroll
        for (int ks = 0; ks < 4; ks++) {
            bf16x8 a;
            if (t < TT) {
                const float* p = outb + ((size_t)b * TT + t) * 128 + 32 * ks + 8 * lhi;
                const float4 lo = *(const float4*)p;
                const float4 hi = *(const float4*)(p + 4);
                a[0] = f2bf(lo.x); a[1] = f2bf(lo.y); a[2] = f2bf(lo.z); a[3] = f2bf(lo.w);
                a[4] = f2bf(hi.x); a[5] = f2bf(hi.y); a[6] = f2bf(hi.z); a[7] = f2bf(hi.w);
            } else {
                #pragma unroll
                for (int jj = 0; jj < 8; jj++) a[jj] = 0;
            }
            #pragma unroll
            for (int nt = 0; nt < 4; nt++) {
                const bf16x8 bf = *(const bf16x8*)&wk_sw[(ks * 256 + lhi * 64 + nt * 16 + l15) * 8];
                acc[nt] = __builtin_amdgcn_mfma_f32_16x16x32_bf16(a, bf, acc[nt], 0, 0, 0);
            }
        }
        // energy partials: ep[r] = sum_c We[c] * tanh(keys[t0+4*lhi+r][c] + q[c]); c spread over l15 x nt
        float ep0 = 0.f, ep1 = 0.f, ep2 = 0.f, ep3 = 0.f;
        #pragma unroll
        for (int nt = 0; nt < 4; nt++) {
            const int c = 16 * nt + l15;
            const float qn = q_lds[c];
            const float wen = we_lds[c];
            ep0 = fmaf(wen, ftanh(acc[nt][0] + qn), ep0);
            ep1 = fmaf(wen, ftanh(acc[nt][1] + qn), ep1);
            ep2 = fmaf(wen, ftanh(acc[nt][2] + qn), ep2);
            ep3 = fmaf(wen, ftanh(acc[nt][3] + qn), ep3);
        }
        #pragma unroll
        for (int off = 1; off < 16; off <<= 1) {
            ep0 += __shfl_xor(ep0, off);
            ep1 += __shfl_xor(ep1, off);
            ep2 += __shfl_xor(ep2, off);
            ep3 += __shfl_xor(ep3, off);
        }
        if (l15 == 0) {
            const int rbase = t0 + 4 * lhi;
            if (rbase + 0 < TT) e_lds[rbase + 0] = ep0;
            if (rbase + 1 < TT) e_lds[rbase + 1] = ep1;
            if (rbase + 2 < TT) e_lds[rbase + 2] = ep2;
            if (rbase + 3 < TT) e_lds[rbase + 3] = ep3;
        }
    }
    __syncthreads();
    // softmax over t (wave 0)
    if (w == 0) {
        const float bev = be[0];
        for (int t = lane; t < TT; t += 64) {
            float e = e_lds[t] + bev;
            if (ids[(size_t)b * TT + t] == 0) e -= 1e9f;
            e_lds[t] = e;
        }
        float m = -1e30f;
        for (int t = lane; t < TT; t += 64) m = fmaxf(m, e_lds[t]);
        #pragma unroll
        for (int off = 32; off > 0; off >>= 1) m = fmaxf(m, __shfl_xor(m, off));
        float ssum = 0.f;
        for (int t = lane; t < TT; t += 64) { const float v = __expf(e_lds[t] - m); e_lds[t] = v; ssum += v; }
        #pragma unroll
        for (int off = 32; off > 0; off >>= 1) ssum += __shfl_xor(ssum, off);
        const float inv = 1.f / ssum;
        for (int t = lane; t < TT; t += 64) e_lds[t] *= inv;
    }
    __syncthreads();
    // context (fp32): wave w covers t ≡ w (mod 4)
    float c0 = 0.f, c1 = 0.f;
    for (int t = w; t < TT; t += 4) {
        const float* orow = outb + ((size_t)b * TT + t) * 128;
        const float wt = e_lds[t];
        c0 = fmaf(wt, orow[lane], c0);
        c1 = fmaf(wt, orow[64 + lane], c1);
    }
    part[w][lane] = c0;
    part[w][64 + lane] = c1;
    __syncthreads();
    if (tid < 128)
        ctx[(size_t)b * 128 + tid] = part[0][tid] + part[1][tid] + part[2][tid] + part[3][tid];
}

// ---------------- (fallback) GRU 3-wave kernel, recompute-gx variant ----------------
template<bool USE_EMBW>
__global__ __launch_bounds__(192, 2) void gru_kernel(
    const int* __restrict__ ids,
    const float* __restrict__ embW_f, const float* __restrict__ embW_b,
    const float* __restrict__ emb,
    const float* __restrict__ Wx_f, const float* __restrict__ bi_f,
    const float* __restrict__ Wx_b, const float* __restrict__ bi_b,
    const float* __restrict__ Wh_f, const float* __restrict__ br_f,
    const float* __restrict__ Wh_b, const float* __restrict__ br_b,
    float* __restrict__ outb, float* __restrict__ hf_out)
{
    constexpr int R = 4;
    __shared__ float h_lds[R][64];
    __shared__ float rg_lds[R][64];
    __shared__ float hh_lds[R][64];
    __shared__ int ids_lds[R * TT];
    const int tid = threadIdx.x;
    const int w = tid >> 6;
    const int j = tid & 63;
    const int dir = blockIdx.y;
    const int b0 = blockIdx.x * R;
    const float* embW = dir ? embW_b : embW_f;
    const float* Wh   = dir ? Wh_b : Wh_f;
    const float* br   = dir ? br_b : br_f;
    const float* Wx   = dir ? Wx_b : Wx_f;
    const float* bi   = dir ? bi_b : bi_f;
    const int c = w * 64 + j;

    float whc[64];
    #pragma unroll
    for (int k = 0; k < 64; k++) whc[k] = Wh[k * 192 + c];
    const float brc = br[c];
    float wxc[EE];
    float bic = 0.f;
    if (!USE_EMBW) {
        #pragma unroll
        for (int k = 0; k < EE; k++) wxc[k] = Wx[k * 192 + c];
        bic = bi[c];
    }
    for (int i = tid; i < R * TT; i += 192) ids_lds[i] = ids[(size_t)b0 * TT + i];
    if (w == 0) {
        #pragma unroll
        for (int r = 0; r < R; r++) h_lds[r][j] = 0.f;
    }
    __syncthreads();

    for (int s = 0; s < TT; s++) {
        const int t = dir ? (TT - 1 - s) : s;
        int idv[R];
        float gxv[R], accv[R];
        #pragma unroll
        for (int r = 0; r < R; r++) idv[r] = ids_lds[r * TT + t];
        if (USE_EMBW) {
            #pragma unroll
            for (int r = 0; r < R; r++) gxv[r] = embW[(size_t)idv[r] * 192 + c];
        } else {
            #pragma unroll
            for (int r = 0; r < R; r++) {
                float acc = bic;
                const float* er = emb + (size_t)idv[r] * EE;
                #pragma unroll
                for (int k = 0; k < EE; k++) acc = fmaf(er[k], wxc[k], acc);
                gxv[r] = acc;
            }
        }
        #pragma unroll
        for (int r = 0; r < R; r++) {
            float acc = brc;
            const float4* h4 = (const float4*)(&h_lds[r][0]);
            #pragma unroll
            for (int k4 = 0; k4 < 16; k4++) {
                const float4 hv = h4[k4];
                acc = fmaf(hv.x, whc[4 * k4 + 0], acc);
                acc = fmaf(hv.y, whc[4 * k4 + 1], acc);
                acc = fmaf(hv.z, whc[4 * k4 + 2], acc);
                acc = fmaf(hv.w, whc[4 * k4 + 3], acc);
            }
            accv[r] = acc;
        }
        float zg[R] = {};
        if (w == 1) {
            #pragma unroll
            for (int r = 0; r < R; r++) rg_lds[r][j] = fsig(gxv[r] + accv[r]);
        } else if (w == 0) {
            #pragma unroll
            for (int r = 0; r < R; r++) zg[r] = fsig(gxv[r] + accv[r]);
        }
        __syncthreads();
        if (w == 2) {
            #pragma unroll
            for (int r = 0; r < R; r++)
                hh_lds[r][j] = ftanh(gxv[r] + rg_lds[r][j] * accv[r]);
        }
        __syncthreads();
        if (w == 0) {
            #pragma unroll
            for (int r = 0; r < R; r++) {
                const float hold = h_lds[r][j];
                float hnew = hold;
                if (idv[r] != 0) {
                    const float hh = hh_lds[r][j];
                    hnew = zg[r] * hold + (1.f - zg[r]) * hh;
                }
                h_lds[r][j] = hnew;
                outb[((size_t)(b0 + r) * TT + t) * 128 + dir * 64 + j] = hnew;
            }
        }
        __syncthreads();
    }
    if (dir == 0 && w == 0) {
        #pragma unroll
        for (int r = 0; r < R; r++) hf_out[(size_t)(b0 + r) * 64 + j] = h_lds[r][j];
    }
}

extern "C" void kernel_launch(void* const* d_in, const int* in_sizes, int n_in,
                              void* d_out, int out_size, void* d_ws, size_t ws_size,
                              hipStream_t stream) {
    const int*   ids  = (const int*)d_in[0];
    const float* emb  = (const float*)d_in[1];
    const float* Wx_f = (const float*)d_in[2];
    const float* Wh_f = (const float*)d_in[3];
    const float* bi_f = (const float*)d_in[4];
    const float* br_f = (const float*)d_in[5];
    const float* Wx_b = (const float*)d_in[6];
    const float* Wh_b = (const float*)d_in[7];
    const float* bi_b = (const float*)d_in[8];
    const float* br_b = (const float*)d_in[9];
    const float* Wk   = (const float*)d_in[10];
    const float* bk   = (const float*)d_in[11];
    const float* Wq   = (const float*)d_in[12];
    const float* bq   = (const float*)d_in[13];
    const float* We   = (const float*)d_in[14];
    const float* be   = (const float*)d_in[15];
    float* ctx = (float*)d_out;

    float* ws = (float*)d_ws;
    const size_t embw_elems = (size_t)VV * 192;
    const size_t out_elems  = (size_t)BB * TT * 128;
    const size_t hf_elems   = (size_t)BB * 64;
    const size_t need_embw  = (2 * embw_elems + out_elems + hf_elems) * sizeof(float);
    const bool use_embw = (ws_size >= need_embw);

    float *embW_f = nullptr, *embW_b = nullptr, *outb, *hf;
    if (use_embw) {
        embW_f = ws;
        embW_b = embW_f + embw_elems;
        outb   = embW_b + embw_elems;
        hf     = outb + out_elems;
    } else {
        outb = ws;
        hf   = outb + out_elems;
    }

    if (use_embw) {
        embw_kernel<<<dim3(VV / 32, 2), 256, 0, stream>>>(
            emb, Wx_f, bi_f, Wx_b, bi_b, embW_f, embW_b);
        gru5_kernel<<<dim3(BB, 2), 64, 0, stream>>>(
            ids, embW_f, embW_b, Wh_f, br_f, Wh_b, br_b, outb, hf);
    } else {
        gru_kernel<false><<<dim3(BB / 4, 2), 192, 0, stream>>>(
            ids, embW_f, embW_b, emb, Wx_f, bi_f, Wx_b, bi_b,
            Wh_f, br_f, Wh_b, br_b, outb, hf);
    }
    attn7_kernel<<<BB, 256, 0, stream>>>(ids, outb, hf, Wk, bk, Wq, bq, We, be, ctx);
}